// Round 1
// baseline (37.733 us; speedup 1.0000x reference)
//
#include <hip/hip_runtime.h>

namespace {

constexpr int FHc = 3, FWc = 3;
constexpr int Bc = 8, Cc = 32, Hc = 32, Wc = 32, Oc = 64;
constexpr int HOc = 30, WOc = 30;
constexpr float SHIFTc = 0.1f;
constexpr int ROWW = 12;                 // padded LDS row (10 used) -> 48B, float4-aligned
constexpr int TILE_F = Cc * FHc * ROWW;  // 1152 floats per (lp|ln) tile

#define LOADROW(dst, base) do {                                         \
    const float4 _a = *reinterpret_cast<const float4*>(base);           \
    const float4 _b = *reinterpret_cast<const float4*>((base) + 4);     \
    const float2 _c = *reinterpret_cast<const float2*>((base) + 8);     \
    dst[0]=_a.x; dst[1]=_a.y; dst[2]=_a.z; dst[3]=_a.w;                 \
    dst[4]=_b.x; dst[5]=_b.y; dst[6]=_b.z; dst[7]=_b.w;                 \
    dst[8]=_c.x; dst[9]=_c.y; } while (0)

__global__ __launch_bounds__(256)
void bipolar_morph2d(const float* __restrict__ x,
                     const float* __restrict__ k1,
                     const float* __restrict__ k2,
                     const float* __restrict__ bias,
                     float* __restrict__ out)
{
    // 32 KiB shared: used first as lp/ln tile (2*1152 floats), then as the
    // cross-wave partial-max buffer (4 waves * 4 branches * 8 s * 64 o = 8192 floats).
    __shared__ float sh[8192];
    float* lp = sh;
    float* ln = sh + TILE_F;

    const int tid = threadIdx.x;
    const int bid = blockIdx.x;
    const int wt  = bid & 3;             // which wo-tile of 8
    const int ho  = (bid >> 2) % HOc;
    const int b   = bid / (4 * HOc);
    const int wo0 = wt * 8;

    // ---- stage: lp = log(max(x,0.1)), ln = log(max(-x,0.1)) for 3x10 x C halo ----
    for (int e = tid; e < Cc * FHc * 10; e += 256) {
        const int c   = e / 30;
        const int rem = e - c * 30;
        const int i   = rem / 10;
        const int w   = rem - i * 10;
        int col = wo0 + w; if (col > Wc - 1) col = Wc - 1;   // clamp (only wt==3, s>=6 -> unused)
        const float xv = x[((b * Cc + c) * Hc + (ho + i)) * Wc + col];
        lp[(c * FHc + i) * ROWW + w] = __logf(fmaxf(xv,  SHIFTc));
        ln[(c * FHc + i) * ROWW + w] = __logf(fmaxf(-xv, SHIFTc));
    }
    __syncthreads();

    const int wv    = tid >> 6;   // wave id: owns c-chunk [8*wv, 8*wv+8)
    const int o     = tid & 63;   // lane = output channel
    const int cbase = wv * 8;

    float m11[8], m12[8], m21[8], m22[8];
    #pragma unroll
    for (int s = 0; s < 8; ++s) m11[s] = m12[s] = m21[s] = m22[s] = -1e30f;

    for (int cc = 0; cc < 8; cc += 2) {
        const int c0 = cbase + cc;
        #pragma unroll
        for (int i = 0; i < FHc; ++i) {
            // 4 rows of 10 floats, wave-uniform LDS broadcast reads
            float r_lp0[10], r_ln0[10], r_lp1[10], r_ln1[10];
            const float* bp0 = &lp[(c0 * FHc + i) * ROWW];
            const float* bn0 = &ln[(c0 * FHc + i) * ROWW];
            LOADROW(r_lp0, bp0);
            LOADROW(r_ln0, bn0);
            LOADROW(r_lp1, bp0 + FHc * ROWW);   // c0+1
            LOADROW(r_ln1, bn0 + FHc * ROWW);
            #pragma unroll
            for (int j = 0; j < FWc; ++j) {
                const int p0 = ((i * FWc + j) * Cc + c0) * Oc + o;
                const float k1a = k1[p0], k1b = k1[p0 + Oc];
                const float k2a = k2[p0], k2b = k2[p0 + Oc];
                #pragma unroll
                for (int s = 0; s < 8; ++s) {
                    // fmaxf(fmaxf(m,a0),a1) -> v_max3_f32
                    m11[s] = fmaxf(fmaxf(m11[s], r_lp0[j + s] + k1a), r_lp1[j + s] + k1b);
                    m12[s] = fmaxf(fmaxf(m12[s], r_lp0[j + s] + k2a), r_lp1[j + s] + k2b);
                    m21[s] = fmaxf(fmaxf(m21[s], r_ln0[j + s] + k1a), r_ln1[j + s] + k1b);
                    m22[s] = fmaxf(fmaxf(m22[s], r_ln0[j + s] + k2a), r_ln1[j + s] + k2b);
                }
            }
        }
    }

    // ---- cross-wave max reduction (each wave covered 8 of 32 channels) ----
    __syncthreads();   // all tile reads done; safe to overwrite sh
    #pragma unroll
    for (int s = 0; s < 8; ++s) {
        sh[((wv * 4 + 0) * 8 + s) * 64 + o] = m11[s];
        sh[((wv * 4 + 1) * 8 + s) * 64 + o] = m12[s];
        sh[((wv * 4 + 2) * 8 + s) * 64 + o] = m21[s];
        sh[((wv * 4 + 3) * 8 + s) * 64 + o] = m22[s];
    }
    __syncthreads();

    const float bo = bias[o];
    #pragma unroll
    for (int t = 0; t < 2; ++t) {
        const int s  = 2 * wv + t;        // each wave finalizes 2 spatial positions
        const int wo = wo0 + s;
        if (wo < WOc) {
            float f[4];
            #pragma unroll
            for (int br = 0; br < 4; ++br) {
                const float v0 = sh[((0 * 4 + br) * 8 + s) * 64 + o];
                const float v1 = sh[((1 * 4 + br) * 8 + s) * 64 + o];
                const float v2 = sh[((2 * 4 + br) * 8 + s) * 64 + o];
                const float v3 = sh[((3 * 4 + br) * 8 + s) * 64 + o];
                f[br] = fmaxf(fmaxf(v0, v1), fmaxf(v2, v3));
            }
            out[((b * Oc + o) * HOc + ho) * WOc + wo] =
                __expf(f[0]) - __expf(f[1]) - __expf(f[2]) + __expf(f[3]) + bo;
        }
    }
}

} // namespace

extern "C" void kernel_launch(void* const* d_in, const int* in_sizes, int n_in,
                              void* d_out, int out_size, void* d_ws, size_t ws_size,
                              hipStream_t stream) {
    const float* x    = (const float*)d_in[0];
    const float* k1   = (const float*)d_in[1];
    const float* k2   = (const float*)d_in[2];
    const float* bias = (const float*)d_in[3];
    float* out        = (float*)d_out;

    const int nblocks = Bc * HOc * 4;   // 8 * 30 * 4 = 960
    bipolar_morph2d<<<dim3(nblocks), dim3(256), 0, stream>>>(x, k1, k2, bias, out);
}

// Round 2
// 28.442 us; speedup vs baseline: 1.3267x; 1.3267x over previous
//
#include <hip/hip_runtime.h>

namespace {

constexpr int FHc = 3, FWc = 3;
constexpr int Bc = 8, Cc = 32, Hc = 32, Wc = 32, Oc = 64;
constexpr int HOc = 30, WOc = 30;
constexpr float SHIFTc = 0.1f;
constexpr int ROWW = 12;                 // padded LDS row (10 used) -> 48B, float4-aligned
constexpr int TILE_F = Cc * FHc * ROWW;  // 1152 floats per (lp|ln) tile

#define LOADROW(dst, base) do {                                         \
    const float4 _a = *reinterpret_cast<const float4*>(base);           \
    const float4 _b = *reinterpret_cast<const float4*>((base) + 4);     \
    const float2 _c = *reinterpret_cast<const float2*>((base) + 8);     \
    dst[0]=_a.x; dst[1]=_a.y; dst[2]=_a.z; dst[3]=_a.w;                 \
    dst[4]=_b.x; dst[5]=_b.y; dst[6]=_b.z; dst[7]=_b.w;                 \
    dst[8]=_c.x; dst[9]=_c.y; } while (0)

__global__ __launch_bounds__(512)
void bipolar_morph2d(const float* __restrict__ x,
                     const float* __restrict__ k1,
                     const float* __restrict__ k2,
                     const float* __restrict__ bias,
                     float* __restrict__ out)
{
    // 32 KiB shared: lp/ln tile (2*1152 floats) first, then a 8192-float
    // partial-max buffer reused in two reduction phases (4 waves' worth each).
    __shared__ float sh[8192];
    float* lp = sh;
    float* ln = sh + TILE_F;

    const int tid = threadIdx.x;
    const int bid = blockIdx.x;
    const int wt  = bid & 3;             // which wo-tile of 8
    const int ho  = (bid >> 2) % HOc;
    const int b   = bid / (4 * HOc);
    const int wo0 = wt * 8;

    // ---- stage: lp = log(max(x,0.1)), ln = log(max(-x,0.1)) for 3x10 x C halo ----
    for (int e = tid; e < Cc * FHc * 10; e += 512) {
        const int c   = e / 30;
        const int rem = e - c * 30;
        const int i   = rem / 10;
        const int w   = rem - i * 10;
        int col = wo0 + w; if (col > Wc - 1) col = Wc - 1;   // clamp (only wt==3, s>=6 -> unused)
        const float xv = x[((b * Cc + c) * Hc + (ho + i)) * Wc + col];
        lp[(c * FHc + i) * ROWW + w] = __logf(fmaxf(xv,  SHIFTc));
        ln[(c * FHc + i) * ROWW + w] = __logf(fmaxf(-xv, SHIFTc));
    }
    __syncthreads();

    const int wv    = tid >> 6;   // wave id 0..7: owns c-chunk [4*wv, 4*wv+4)
    const int o     = tid & 63;   // lane = output channel
    const int cbase = wv * 4;

    float m11[8], m12[8], m21[8], m22[8];
    #pragma unroll
    for (int s = 0; s < 8; ++s) m11[s] = m12[s] = m21[s] = m22[s] = -1e30f;

    #pragma unroll
    for (int cc = 0; cc < 4; cc += 2) {
        const int c0 = cbase + cc;
        #pragma unroll
        for (int i = 0; i < FHc; ++i) {
            // 4 rows of 10 floats, wave-uniform LDS broadcast reads
            float r_lp0[10], r_ln0[10], r_lp1[10], r_ln1[10];
            const float* bp0 = &lp[(c0 * FHc + i) * ROWW];
            const float* bn0 = &ln[(c0 * FHc + i) * ROWW];
            LOADROW(r_lp0, bp0);
            LOADROW(r_ln0, bn0);
            LOADROW(r_lp1, bp0 + FHc * ROWW);   // c0+1
            LOADROW(r_ln1, bn0 + FHc * ROWW);
            #pragma unroll
            for (int j = 0; j < FWc; ++j) {
                const int p0 = ((i * FWc + j) * Cc + c0) * Oc + o;
                const float k1a = k1[p0], k1b = k1[p0 + Oc];
                const float k2a = k2[p0], k2b = k2[p0 + Oc];
                #pragma unroll
                for (int s = 0; s < 8; ++s) {
                    // fmaxf(fmaxf(m,a0),a1) -> v_max3_f32
                    m11[s] = fmaxf(fmaxf(m11[s], r_lp0[j + s] + k1a), r_lp1[j + s] + k1b);
                    m12[s] = fmaxf(fmaxf(m12[s], r_lp0[j + s] + k2a), r_lp1[j + s] + k2b);
                    m21[s] = fmaxf(fmaxf(m21[s], r_ln0[j + s] + k1a), r_ln1[j + s] + k1b);
                    m22[s] = fmaxf(fmaxf(m22[s], r_ln0[j + s] + k2a), r_ln1[j + s] + k2b);
                }
            }
        }
    }

    // ---- cross-wave max reduction: 8 waves -> 4 -> 1, reusing one 32 KiB buffer ----
    __syncthreads();   // tile reads done; safe to overwrite sh

    // Phase A: upper 4 waves publish, lower 4 merge into registers.
    if (wv >= 4) {
        const int lw = wv - 4;
        #pragma unroll
        for (int s = 0; s < 8; ++s) {
            sh[((lw * 4 + 0) * 8 + s) * 64 + o] = m11[s];
            sh[((lw * 4 + 1) * 8 + s) * 64 + o] = m12[s];
            sh[((lw * 4 + 2) * 8 + s) * 64 + o] = m21[s];
            sh[((lw * 4 + 3) * 8 + s) * 64 + o] = m22[s];
        }
    }
    __syncthreads();
    if (wv < 4) {
        #pragma unroll
        for (int s = 0; s < 8; ++s) {
            m11[s] = fmaxf(m11[s], sh[((wv * 4 + 0) * 8 + s) * 64 + o]);
            m12[s] = fmaxf(m12[s], sh[((wv * 4 + 1) * 8 + s) * 64 + o]);
            m21[s] = fmaxf(m21[s], sh[((wv * 4 + 2) * 8 + s) * 64 + o]);
            m22[s] = fmaxf(m22[s], sh[((wv * 4 + 3) * 8 + s) * 64 + o]);
        }
    }
    __syncthreads();
    // Phase B: lower 4 waves publish merged partials.
    if (wv < 4) {
        #pragma unroll
        for (int s = 0; s < 8; ++s) {
            sh[((wv * 4 + 0) * 8 + s) * 64 + o] = m11[s];
            sh[((wv * 4 + 1) * 8 + s) * 64 + o] = m12[s];
            sh[((wv * 4 + 2) * 8 + s) * 64 + o] = m21[s];
            sh[((wv * 4 + 3) * 8 + s) * 64 + o] = m22[s];
        }
    }
    __syncthreads();

    // ---- finalize: each wave owns one spatial position s = wv ----
    const int s  = wv;
    const int wo = wo0 + s;
    if (wo < WOc) {
        const float bo = bias[o];
        float f[4];
        #pragma unroll
        for (int br = 0; br < 4; ++br) {
            const float v0 = sh[((0 * 4 + br) * 8 + s) * 64 + o];
            const float v1 = sh[((1 * 4 + br) * 8 + s) * 64 + o];
            const float v2 = sh[((2 * 4 + br) * 8 + s) * 64 + o];
            const float v3 = sh[((3 * 4 + br) * 8 + s) * 64 + o];
            f[br] = fmaxf(fmaxf(v0, v1), fmaxf(v2, v3));
        }
        out[((b * Oc + o) * HOc + ho) * WOc + wo] =
            __expf(f[0]) - __expf(f[1]) - __expf(f[2]) + __expf(f[3]) + bo;
    }
}

} // namespace

extern "C" void kernel_launch(void* const* d_in, const int* in_sizes, int n_in,
                              void* d_out, int out_size, void* d_ws, size_t ws_size,
                              hipStream_t stream) {
    const float* x    = (const float*)d_in[0];
    const float* k1   = (const float*)d_in[1];
    const float* k2   = (const float*)d_in[2];
    const float* bias = (const float*)d_in[3];
    float* out        = (float*)d_out;

    const int nblocks = Bc * HOc * 4;   // 8 * 30 * 4 = 960
    bipolar_morph2d<<<dim3(nblocks), dim3(512), 0, stream>>>(x, k1, k2, bias, out);
}